// Round 1
// 1349.960 us; speedup vs baseline: 4.8985x; 4.8985x over previous
//
#include <hip/hip_runtime.h>

#define B_   32
#define NP_  192
#define C_   128
#define NS_  36
#define MID_ 64
#define FCH_ 128
#define RH_  10
#define RW_  25
#define FH_  40
#define FW_  100
#define L_   250
#define NR_  (B_*NP_)
#define EPS_ 1e-5f

// ---- MFMA fused-ROI geometry ----
#define G_    4            // ROIs per block -> N = 144 = 9 x 16
#define XROWS 44           // 4 zero-pad + 36 + 4 zero-pad rows (tap shifts branch-free)
#define CPX   136          // Xt row stride in f16 (272B = 17*16B, odd 16B multiple)
#define CPC   200          // cst row stride in f16 (400B = 25*16B, odd 16B multiple)

typedef _Float16 f16;
typedef f16   f16x8 __attribute__((ext_vector_type(8)));
typedef f16   f16x4 __attribute__((ext_vector_type(4)));
typedef float f32x4 __attribute__((ext_vector_type(4)));

#define MFMA16(a,b,c) __builtin_amdgcn_mfma_f32_16x16x32_f16((a),(b),(c),0,0,0)

// ---- workspace layout (bytes) ----
#define WS_KBUF   0u                       // B*C*L*4   = 4,096,000
#define WS_VBUF   4096000u                 // B*L*C*4   = 4,096,000
#define WS_CONVWT 8192000u                 // f16 [3][9][64][128]  = 442,368 B
#define WS_CATWT  (WS_CONVWT + 442368u)    // f16 [9][128][192]    = 442,368 B
#define WS_FCWH   (WS_CATWT + 442368u)     // f16 [128][4608]      = 1,179,648 B
// total ws = 10,256,384 B

// ---------------------------------------------------------------------------
// Prep: transpose weights to MFMA-friendly f16 layouts (k-dim contiguous).
// conv_w (3,64,128,9)->[lev][tap][oc][cin]; cat_w (128,192,9)->[tap][oc][cin];
// fc_w (128,4608) -> f16 same layout.
// ---------------------------------------------------------------------------
__global__ __launch_bounds__(256) void k_prep(
    const float* __restrict__ conv_w, const float* __restrict__ cat_w,
    const float* __restrict__ fc_w,
    f16* __restrict__ cwt, f16* __restrict__ kwt, f16* __restrict__ fwh)
{
  int i = blockIdx.x * 256 + threadIdx.x;
  if (i < 221184) {
    int cin = i & 127;
    int r   = i >> 7;
    int oc  = r & 63; r >>= 6;
    int tap = r % 9, lev = r / 9;
    cwt[i] = (f16)conv_w[(((size_t)(lev*64 + oc))*128 + cin)*9 + tap];
  } else if (i < 442368) {
    int j   = i - 221184;
    int cin = j % 192;
    int r   = j / 192;
    int oc  = r & 127;
    int tap = r >> 7;
    kwt[j] = (f16)cat_w[((size_t)oc*192 + cin)*9 + tap];
  } else if (i < 1032192) {
    int k = i - 442368;
    fwh[k] = (f16)fc_w[k];
  }
}

// ---------------------------------------------------------------------------
// K1 (fused, MFMA): 3x level conv9+BN+ReLU -> catconv9+BN+ReLU -> fc+LN+ReLU.
// One block per 4 ROIs, 512 threads (8 waves).  A/B frag mapping (16x16x32):
// A: row=lane&15, k=(lane>>4)*8+j ; B: col=lane&15, k=(lane>>4)*8+j ;
// D: col=lane&15, row=(lane>>4)*4+reg.
// ---------------------------------------------------------------------------
__global__ __launch_bounds__(512) void k_roi(
    const float* __restrict__ rf0, const float* __restrict__ rf1, const float* __restrict__ rf2,
    const f16* __restrict__ cwt, const f16* __restrict__ kwt, const f16* __restrict__ fwh,
    const float* __restrict__ cg, const float* __restrict__ cb,
    const float* __restrict__ cm, const float* __restrict__ cv,
    const float* __restrict__ wg, const float* __restrict__ wb,
    const float* __restrict__ wm, const float* __restrict__ wvv,
    const float* __restrict__ fcb, const float* __restrict__ lng, const float* __restrict__ lnb,
    float* __restrict__ roi)
{
  // LDS pool: Xt [4][44][136] f16 (47,872 B)  | cst [4][44][200] f16 (70,400 B)
  //           | scr 512 f32 (2 KB) | hs 512 f32 (2 KB)   => 122,368 B
  __shared__ __align__(16) char smem[122368];
  f16*   Xt  = (f16*)smem;                 // stage-1 input (aliased by Yh later)
  f16*   Yh  = (f16*)smem;                 // [4][4608] catconv output (36,864 B)
  f16*   cst = (f16*)(smem + 47872);       // concat of level-conv outputs
  float* scr = (float*)(smem + 118272);    // fc partials / LN scratch
  float* hs  = (float*)(smem + 120320);    // [4][128] fc+bias pre-LN

  const int tid  = threadIdx.x, lane = tid & 63, w = tid >> 6;
  const int r16  = lane & 15, g4 = lane >> 4;
  const int nbase = blockIdx.x * G_;

  // ---- zero the pad rows (0-3, 40-43) of Xt and cst once ----
  for (int i = tid; i < G_*8*CPX; i += 512) {
    int rr = i / CPX, col = i - rr*CPX;
    int g = rr >> 3, r8 = rr & 7;
    int row = (r8 < 4) ? r8 : (36 + r8);
    Xt[(g*XROWS + row)*CPX + col] = (f16)0.f;
  }
  for (int i = tid; i < G_*8*CPC; i += 512) {
    int rr = i / CPC, col = i - rr*CPC;
    int g = rr >> 3, r8 = rr & 7;
    int row = (r8 < 4) ? r8 : (36 + r8);
    cst[(g*XROWS + row)*CPC + col] = (f16)0.f;
  }

  // ---- conv-stage wave roles: mh = M-half, nq -> N tiles {nq, nq+4, nq+8} ----
  const int mh = w & 1, nq = w >> 1;
  const int nNT = (nq == 0) ? 3 : 2;
  int xoff[3], coffR[3], coffW[3], gq[3], sq[3];
  #pragma unroll
  for (int nl = 0; nl < 3; nl++) {
    int nt = nq + 4*nl; if (nt > 8) nt = 8;     // clamped slot only used when guarded
    int q = nt*16 + r16;
    int g = q / 36, s = q - 36*g;
    gq[nl] = g; sq[nl] = s;
    xoff[nl]  = (g*XROWS + s)*CPX + g4*8;       // + tap*CPX + c0 at use
    coffR[nl] = (g*XROWS + s)*CPC + g4*8;       // stage-2 B read base
    coffW[nl] = (g*XROWS + 4 + s)*CPC;          // stage-1 write row base
  }

  // ================= stage 1: per-level conv9 + BN + ReLU -> cst =================
  for (int lev = 0; lev < 3; lev++) {
    { // cooperative load + transpose + f16 convert: rf[n][c][s] -> Xt[g][4+s][c]
      int g = tid >> 7, t = tid & 127;
      const float* src = (lev == 0 ? rf0 : (lev == 1 ? rf1 : rf2))
                         + (size_t)(nbase + g) * (C_*NS_);
      for (int it = 0; it < 9; it++) {
        int idx = t + 128*it;                 // float4 unit: 1152 per ROI
        int c = idx / 9, s4 = (idx - 9*c)*4;
        float4 v = *(const float4*)(src + c*NS_ + s4);
        f16* dst = Xt + (g*XROWS + 4 + s4)*CPX + c;
        dst[0*CPX] = (f16)v.x; dst[1*CPX] = (f16)v.y;
        dst[2*CPX] = (f16)v.z; dst[3*CPX] = (f16)v.w;
      }
    }
    __syncthreads();

    f32x4 acc[2][3];
    #pragma unroll
    for (int ml = 0; ml < 2; ml++)
      #pragma unroll
      for (int nl = 0; nl < 3; nl++) { f32x4 z = {0.f,0.f,0.f,0.f}; acc[ml][nl] = z; }

    const f16* wl = cwt + (size_t)lev*9*64*128;
    for (int ks = 0; ks < 36; ks++) {
      int tap = ks >> 2, c0 = (ks & 3) << 5;
      const f16* wt = wl + tap*(64*128) + r16*128 + c0 + g4*8;
      f16x8 a0 = *(const f16x8*)(wt + (2*mh+0)*16*128);
      f16x8 a1 = *(const f16x8*)(wt + (2*mh+1)*16*128);
      int xo = tap*CPX + c0;
      f16x8 b0 = *(const f16x8*)(Xt + xoff[0] + xo);
      f16x8 b1 = *(const f16x8*)(Xt + xoff[1] + xo);
      acc[0][0] = MFMA16(a0, b0, acc[0][0]);
      acc[1][0] = MFMA16(a1, b0, acc[1][0]);
      acc[0][1] = MFMA16(a0, b1, acc[0][1]);
      acc[1][1] = MFMA16(a1, b1, acc[1][1]);
      if (nNT == 3) {
        f16x8 b2 = *(const f16x8*)(Xt + xoff[2] + xo);
        acc[0][2] = MFMA16(a0, b2, acc[0][2]);
        acc[1][2] = MFMA16(a1, b2, acc[1][2]);
      }
    }

    #pragma unroll
    for (int ml = 0; ml < 2; ml++) {
      int mt  = 2*mh + ml;
      int ocl = mt*16 + g4*4;          // local oc of reg 0
      int ocg = lev*64 + ocl;          // BN param index
      float sc[4], sh[4];
      #pragma unroll
      for (int r = 0; r < 4; r++) {
        float s0 = cg[ocg+r] * rsqrtf(cv[ocg+r] + EPS_);
        sc[r] = s0; sh[r] = cb[ocg+r] - cm[ocg+r]*s0;
      }
      #pragma unroll
      for (int nl = 0; nl < 3; nl++) if (nl < nNT) {
        f16x4 o;
        #pragma unroll
        for (int r = 0; r < 4; r++)
          o[r] = (f16)fmaxf(fmaf(sc[r], acc[ml][nl][r], sh[r]), 0.f);
        *(f16x4*)(cst + coffW[nl] + lev*64 + ocl) = o;   // ds_write_b64
      }
    }
    __syncthreads();   // Xt reads done before next level load; cst visible after lev 2
  }

  // ================= stage 2: catconv9 + BN + ReLU -> Yh (f16) =================
  {
    f32x4 acc[4][3];
    #pragma unroll
    for (int ml = 0; ml < 4; ml++)
      #pragma unroll
      for (int nl = 0; nl < 3; nl++) { f32x4 z = {0.f,0.f,0.f,0.f}; acc[ml][nl] = z; }

    int tap = 0, c6 = 0;
    for (int ks = 0; ks < 54; ks++) {
      int c0 = c6 << 5;
      const f16* wt = kwt + (size_t)(tap*128 + 4*mh*16 + r16)*192 + c0 + g4*8;
      f16x8 a0 = *(const f16x8*)(wt + 0*16*192);
      f16x8 a1 = *(const f16x8*)(wt + 1*16*192);
      f16x8 a2 = *(const f16x8*)(wt + 2*16*192);
      f16x8 a3 = *(const f16x8*)(wt + 3*16*192);
      int co = tap*CPC + c0;
      f16x8 b0 = *(const f16x8*)(cst + coffR[0] + co);
      f16x8 b1 = *(const f16x8*)(cst + coffR[1] + co);
      acc[0][0] = MFMA16(a0, b0, acc[0][0]);
      acc[1][0] = MFMA16(a1, b0, acc[1][0]);
      acc[2][0] = MFMA16(a2, b0, acc[2][0]);
      acc[3][0] = MFMA16(a3, b0, acc[3][0]);
      acc[0][1] = MFMA16(a0, b1, acc[0][1]);
      acc[1][1] = MFMA16(a1, b1, acc[1][1]);
      acc[2][1] = MFMA16(a2, b1, acc[2][1]);
      acc[3][1] = MFMA16(a3, b1, acc[3][1]);
      if (nNT == 3) {
        f16x8 b2 = *(const f16x8*)(cst + coffR[2] + co);
        acc[0][2] = MFMA16(a0, b2, acc[0][2]);
        acc[1][2] = MFMA16(a1, b2, acc[1][2]);
        acc[2][2] = MFMA16(a2, b2, acc[2][2]);
        acc[3][2] = MFMA16(a3, b2, acc[3][2]);
      }
      if (++c6 == 6) { c6 = 0; tap++; }
    }

    #pragma unroll
    for (int ml = 0; ml < 4; ml++) {
      int oc0 = (4*mh + ml)*16 + g4*4;
      float sc[4], sh[4];
      #pragma unroll
      for (int r = 0; r < 4; r++) {
        float s0 = wg[oc0+r] * rsqrtf(wvv[oc0+r] + EPS_);
        sc[r] = s0; sh[r] = wb[oc0+r] - wm[oc0+r]*s0;
      }
      #pragma unroll
      for (int nl = 0; nl < 3; nl++) if (nl < nNT) {
        int yb = gq[nl]*4608 + oc0*36 + sq[nl];   // Yh aliases dead Xt region
        #pragma unroll
        for (int r = 0; r < 4; r++)
          Yh[yb + r*36] = (f16)fmaxf(fmaf(sc[r], acc[ml][nl][r], sh[r]), 0.f);
      }
    }
  }
  __syncthreads();

  // ================= stage 3: fc via MFMA (N=4 of 16 used) + LN + ReLU =========
  {
    const int mtp = w & 3, kh = w >> 2;   // 2 f-tiles per wave, K split in halves
    const int gcol = r16 & 3;             // cols >=4 compute discarded lanes
    f32x4 fa0 = {0.f,0.f,0.f,0.f}, fa1 = fa0;
    const f16* bb0 = Yh + gcol*4608 + kh*2304 + g4*8;
    const f16* aw0 = fwh + (size_t)((2*mtp+0)*16 + r16)*4608 + kh*2304 + g4*8;
    const f16* aw1 = fwh + (size_t)((2*mtp+1)*16 + r16)*4608 + kh*2304 + g4*8;
    for (int ks = 0; ks < 72; ks++) {
      int k0 = ks*32;
      f16x8 bb = *(const f16x8*)(bb0 + k0);
      f16x8 a0 = *(const f16x8*)(aw0 + k0);
      f16x8 a1 = *(const f16x8*)(aw1 + k0);
      fa0 = MFMA16(a0, bb, fa0);
      fa1 = MFMA16(a1, bb, fa1);
    }
    if (kh == 1 && r16 < 4) {
      #pragma unroll
      for (int r = 0; r < 4; r++) {
        scr[((2*mtp+0)*16 + g4*4 + r)*4 + r16] = fa0[r];
        scr[((2*mtp+1)*16 + g4*4 + r)*4 + r16] = fa1[r];
      }
    }
    __syncthreads();
    if (kh == 0 && r16 < 4) {
      #pragma unroll
      for (int r = 0; r < 4; r++) {
        int f0 = (2*mtp+0)*16 + g4*4 + r;
        int f1 = (2*mtp+1)*16 + g4*4 + r;
        hs[r16*128 + f0] = fa0[r] + scr[f0*4 + r16] + fcb[f0];
        hs[r16*128 + f1] = fa1[r] + scr[f1*4 + r16] + fcb[f1];
      }
    }
  }
  __syncthreads();

  { // LayerNorm + ReLU: wave w handles (g = w>>1, f = (w&1)*64 + lane)
    int g = w >> 1, f = (w & 1)*64 + lane;
    float h = hs[g*128 + f];
    float s1 = h, s2 = h*h;
    #pragma unroll
    for (int off = 32; off; off >>= 1) {
      s1 += __shfl_xor(s1, off, 64);
      s2 += __shfl_xor(s2, off, 64);
    }
    if (lane == 0) { scr[w*2] = s1; scr[w*2+1] = s2; }
    __syncthreads();
    float S1 = scr[(2*g)*2]   + scr[(2*g+1)*2];
    float S2 = scr[(2*g)*2+1] + scr[(2*g+1)*2+1];
    float mu  = S1 * (1.f/128.f);
    float var = S2 * (1.f/128.f) - mu*mu;
    float rr  = rsqrtf(var + EPS_);
    roi[(size_t)(nbase + g)*FCH_ + f] = fmaxf((h - mu)*rr*lng[f] + lnb[f], 0.f);
  }
}

// ---------------------------------------------------------------------------
// K2: key/val projections at the 250 nearest-resize sample points. (unchanged)
// ---------------------------------------------------------------------------
__global__ __launch_bounds__(128) void k_kv(
    const float* __restrict__ fmap,
    const float* __restrict__ kw, const float* __restrict__ kg, const float* __restrict__ kbeta,
    const float* __restrict__ km, const float* __restrict__ kvv,
    const float* __restrict__ vw, const float* __restrict__ vb,
    float* __restrict__ kbuf, float* __restrict__ vbuf)
{
  int l = blockIdx.x, b = blockIdx.y, tid = threadIdx.x;
  int r = l / RW_, s = l % RW_;
  int pix = (r * FH_ / RH_) * FW_ + (s * FW_ / RW_);
  __shared__ float fs[C_];
  fs[tid] = fmap[((size_t)b * C_ + tid) * (FH_ * FW_) + pix];
  __syncthreads();

  int c = tid;
  const float4* kwp = reinterpret_cast<const float4*>(kw + (size_t)c * C_);
  const float4* vwp = reinterpret_cast<const float4*>(vw + (size_t)c * C_);
  float kk = 0.f, vv = 0.f;
  for (int i = 0; i < 32; i++) {
    float4 ku = kwp[i]; float4 vu = vwp[i];
    const float* fb = fs + i * 4;
    kk = fmaf(ku.x, fb[0], kk);  vv = fmaf(vu.x, fb[0], vv);
    kk = fmaf(ku.y, fb[1], kk);  vv = fmaf(vu.y, fb[1], vv);
    kk = fmaf(ku.z, fb[2], kk);  vv = fmaf(vu.z, fb[2], vv);
    kk = fmaf(ku.w, fb[3], kk);  vv = fmaf(vu.w, fb[3], vv);
  }
  float scale = kg[c] * rsqrtf(kvv[c] + EPS_);
  float shift = kbeta[c] - km[c] * scale;
  kbuf[((size_t)b * C_ + c) * L_ + l] = fmaxf(fmaf(scale, kk, shift), 0.f);
  vbuf[((size_t)b * L_ + l) * C_ + c] = vv + vb[c];
}

// ---------------------------------------------------------------------------
// K3: attention per (b, n). In-place on roi buffer. (unchanged)
// ---------------------------------------------------------------------------
__global__ __launch_bounds__(256) void k_attn(
    const float* __restrict__ kbuf, const float* __restrict__ vbuf,
    const float* __restrict__ qw, const float* __restrict__ qb,
    const float* __restrict__ gw, const float* __restrict__ gb,
    float* __restrict__ out)
{
  int nglob = blockIdx.x;
  int b = nglob / NP_, np = nglob % NP_;
  int tid = threadIdx.x;
  __shared__ float qs[C_];
  __shared__ float ps[256];
  __shared__ float rbuf[8];

  float* rp = out + (size_t)nglob * C_;
  if (tid < C_) qs[tid] = fmaxf(fmaf(rp[tid], qw[np], qb[np]), 0.f);
  __syncthreads();

  float sc = -1e30f;
  if (tid < L_) {
    const float* kp = kbuf + (size_t)b * (C_ * L_) + tid;
    float a = 0.f;
    for (int c = 0; c < C_; c++) a = fmaf(qs[c], kp[c * L_], a);
    sc = a * 0.088388347648318447f;
  }
  float m = sc;
  #pragma unroll
  for (int off = 32; off; off >>= 1) m = fmaxf(m, __shfl_xor(m, off, 64));
  if ((tid & 63) == 0) rbuf[tid >> 6] = m;
  __syncthreads();
  m = fmaxf(fmaxf(rbuf[0], rbuf[1]), fmaxf(rbuf[2], rbuf[3]));

  float e = (tid < L_) ? __expf(sc - m) : 0.f;
  ps[tid] = e;
  float s = e;
  #pragma unroll
  for (int off = 32; off; off >>= 1) s += __shfl_xor(s, off, 64);
  if ((tid & 63) == 0) rbuf[4 + (tid >> 6)] = s;
  __syncthreads();
  float S = rbuf[4] + rbuf[5] + rbuf[6] + rbuf[7];
  float inv = 1.f / S;

  if (tid < C_) {
    const float* vp = vbuf + (size_t)b * (L_ * C_) + tid;
    float a = 0.f;
    for (int l = 0; l < L_; l++) a = fmaf(ps[l], vp[l * C_], a);
    a *= inv;
    rp[tid] = rp[tid] + a * gw[np] + gb[np];
  }
}

// ---------------------------------------------------------------------------
extern "C" void kernel_launch(void* const* d_in, const int* in_sizes, int n_in,
                              void* d_out, int out_size, void* d_ws, size_t ws_size,
                              hipStream_t stream)
{
  const float* rf0    = (const float*)d_in[0];
  const float* rf1    = (const float*)d_in[1];
  const float* rf2    = (const float*)d_in[2];
  const float* fmap   = (const float*)d_in[3];
  const float* conv_w = (const float*)d_in[4];
  const float* conv_g = (const float*)d_in[5];
  const float* conv_b = (const float*)d_in[6];
  const float* conv_m = (const float*)d_in[7];
  const float* conv_v = (const float*)d_in[8];
  const float* cat_w  = (const float*)d_in[9];
  const float* cat_g  = (const float*)d_in[10];
  const float* cat_b  = (const float*)d_in[11];
  const float* cat_m  = (const float*)d_in[12];
  const float* cat_v  = (const float*)d_in[13];
  const float* fc_w   = (const float*)d_in[14];
  const float* fc_b   = (const float*)d_in[15];
  const float* ln_g   = (const float*)d_in[16];
  const float* ln_b   = (const float*)d_in[17];
  const float* key_w  = (const float*)d_in[18];
  const float* key_g  = (const float*)d_in[19];
  const float* key_be = (const float*)d_in[20];
  const float* key_m  = (const float*)d_in[21];
  const float* key_v  = (const float*)d_in[22];
  const float* q_w    = (const float*)d_in[23];
  const float* q_b    = (const float*)d_in[24];
  const float* val_w  = (const float*)d_in[25];
  const float* val_b  = (const float*)d_in[26];
  const float* gate_w = (const float*)d_in[27];
  const float* gate_b = (const float*)d_in[28];
  // d_in[29] = layer_index (==2): reference applies cat_w after concat. Unused.

  float* roi  = (float*)d_out;
  char*  ws   = (char*)d_ws;
  float* kbuf = (float*)(ws + WS_KBUF);
  float* vbuf = (float*)(ws + WS_VBUF);
  f16*   cwt  = (f16*)(ws + WS_CONVWT);
  f16*   kwt  = (f16*)(ws + WS_CATWT);
  f16*   fwh  = (f16*)(ws + WS_FCWH);

  k_prep<<<dim3(4032), 256, 0, stream>>>(conv_w, cat_w, fc_w, cwt, kwt, fwh);
  k_kv<<<dim3(L_, B_), 128, 0, stream>>>(fmap, key_w, key_g, key_be, key_m, key_v,
                                         val_w, val_b, kbuf, vbuf);
  k_roi<<<dim3(NR_/G_), 512, 0, stream>>>(rf0, rf1, rf2, cwt, kwt, fwh,
                                          conv_g, conv_b, conv_m, conv_v,
                                          cat_g, cat_b, cat_m, cat_v,
                                          fc_b, ln_g, ln_b, roi);
  k_attn<<<dim3(NR_), 256, 0, stream>>>(kbuf, vbuf, q_w, q_b, gate_w, gate_b, roi);
}

// Round 2
// 1297.499 us; speedup vs baseline: 5.0966x; 1.0404x over previous
//
#include <hip/hip_runtime.h>

#define B_   32
#define NP_  192
#define C_   128
#define NS_  36
#define MID_ 64
#define FCH_ 128
#define RH_  10
#define RW_  25
#define FH_  40
#define FW_  100
#define L_   250
#define NR_  (B_*NP_)
#define EPS_ 1e-5f

// ---- MFMA fused-ROI geometry ----
#define G_    4            // ROIs per block -> N = 144 = 9 x 16
#define XROWS 44           // 4 zero-pad + 36 + 4 zero-pad rows (tap shifts branch-free)
#define CPX   136          // Xt row stride in f16 (272B = 17*16B, odd 16B multiple)
#define CPC   200          // cst row stride in f16 (400B = 25*16B, odd 16B multiple)

typedef _Float16 f16;
typedef f16   f16x8 __attribute__((ext_vector_type(8)));
typedef f16   f16x4 __attribute__((ext_vector_type(4)));
typedef float f32x4 __attribute__((ext_vector_type(4)));

#define MFMA16(a,b,c) __builtin_amdgcn_mfma_f32_16x16x32_f16((a),(b),(c),0,0,0)

// ---- workspace layout (bytes) ----
#define WS_KT     0u                       // f16 [B][256][128] = 2,097,152
#define WS_VT     2097152u                 // f16 [B][128][256] = 2,097,152
#define WS_CONVWT 4194304u                 // f16 [3][9][64][128]  = 442,368
#define WS_CATWT  (WS_CONVWT + 442368u)    // f16 [9][128][192]    = 442,368
#define WS_FCWH   (WS_CATWT + 442368u)     // f16 [128][4608]      = 1,179,648
// total ws = 6,258,688 B

// ---------------------------------------------------------------------------
// Prep: transpose weights to MFMA-friendly f16 layouts (k-dim contiguous).
// ---------------------------------------------------------------------------
__global__ __launch_bounds__(256) void k_prep(
    const float* __restrict__ conv_w, const float* __restrict__ cat_w,
    const float* __restrict__ fc_w,
    f16* __restrict__ cwt, f16* __restrict__ kwt, f16* __restrict__ fwh)
{
  int i = blockIdx.x * 256 + threadIdx.x;
  if (i < 221184) {
    int cin = i & 127;
    int r   = i >> 7;
    int oc  = r & 63; r >>= 6;
    int tap = r % 9, lev = r / 9;
    cwt[i] = (f16)conv_w[(((size_t)(lev*64 + oc))*128 + cin)*9 + tap];
  } else if (i < 442368) {
    int j   = i - 221184;
    int cin = j % 192;
    int r   = j / 192;
    int oc  = r & 127;
    int tap = r >> 7;
    kwt[j] = (f16)cat_w[((size_t)oc*192 + cin)*9 + tap];
  } else if (i < 1032192) {
    int k = i - 442368;
    fwh[k] = (f16)fc_w[k];
  }
}

// ---------------------------------------------------------------------------
// Branch-free MFMA K-loops (NNT hoisted to template) so the scheduler can
// hoist A/B loads far ahead inside one big unrolled basic block.
// ---------------------------------------------------------------------------
template<int NNT>
__device__ __forceinline__ void s1_loop(const f16* __restrict__ wl, const f16* Xt,
    int xoff0, int xoff1, int xoff2, int mh, int r16, int g4, f32x4 acc[2][3])
{
  #pragma unroll
  for (int ks = 0; ks < 36; ks++) {
    const int tap = ks >> 2, c0 = (ks & 3) << 5;
    const f16* wt = wl + tap*(64*128) + r16*128 + c0 + g4*8;
    f16x8 a0 = *(const f16x8*)(wt + (2*mh+0)*16*128);
    f16x8 a1 = *(const f16x8*)(wt + (2*mh+1)*16*128);
    const int xo = tap*CPX + c0;
    f16x8 b0 = *(const f16x8*)(Xt + xoff0 + xo);
    f16x8 b1 = *(const f16x8*)(Xt + xoff1 + xo);
    acc[0][0] = MFMA16(a0, b0, acc[0][0]);
    acc[1][0] = MFMA16(a1, b0, acc[1][0]);
    acc[0][1] = MFMA16(a0, b1, acc[0][1]);
    acc[1][1] = MFMA16(a1, b1, acc[1][1]);
    if (NNT == 3) {
      f16x8 b2 = *(const f16x8*)(Xt + xoff2 + xo);
      acc[0][2] = MFMA16(a0, b2, acc[0][2]);
      acc[1][2] = MFMA16(a1, b2, acc[1][2]);
    }
  }
}

template<int NNT>
__device__ __forceinline__ void s2_loop(const f16* __restrict__ kwt, const f16* cst,
    int co0, int co1, int co2, int mh, int r16, int g4, f32x4 acc[4][3])
{
  #pragma unroll 18
  for (int ks = 0; ks < 54; ks++) {
    const int tap = ks / 6, c0 = (ks % 6) << 5;
    const f16* wt = kwt + (size_t)(tap*128 + 4*mh*16 + r16)*192 + c0 + g4*8;
    f16x8 a0 = *(const f16x8*)(wt + 0*16*192);
    f16x8 a1 = *(const f16x8*)(wt + 1*16*192);
    f16x8 a2 = *(const f16x8*)(wt + 2*16*192);
    f16x8 a3 = *(const f16x8*)(wt + 3*16*192);
    const int co = tap*CPC + c0;
    f16x8 b0 = *(const f16x8*)(cst + co0 + co);
    f16x8 b1 = *(const f16x8*)(cst + co1 + co);
    acc[0][0] = MFMA16(a0, b0, acc[0][0]);
    acc[1][0] = MFMA16(a1, b0, acc[1][0]);
    acc[2][0] = MFMA16(a2, b0, acc[2][0]);
    acc[3][0] = MFMA16(a3, b0, acc[3][0]);
    acc[0][1] = MFMA16(a0, b1, acc[0][1]);
    acc[1][1] = MFMA16(a1, b1, acc[1][1]);
    acc[2][1] = MFMA16(a2, b1, acc[2][1]);
    acc[3][1] = MFMA16(a3, b1, acc[3][1]);
    if (NNT == 3) {
      f16x8 b2 = *(const f16x8*)(cst + co2 + co);
      acc[0][2] = MFMA16(a0, b2, acc[0][2]);
      acc[1][2] = MFMA16(a1, b2, acc[1][2]);
      acc[2][2] = MFMA16(a2, b2, acc[2][2]);
      acc[3][2] = MFMA16(a3, b2, acc[3][2]);
    }
  }
}

// ---------------------------------------------------------------------------
// K1 (fused, MFMA): 3x level conv9+BN+ReLU -> catconv9+BN+ReLU -> fc+LN+ReLU.
// One block per 4 ROIs, 512 threads (8 waves).
// ---------------------------------------------------------------------------
__global__ __launch_bounds__(512) void k_roi(
    const float* __restrict__ rf0, const float* __restrict__ rf1, const float* __restrict__ rf2,
    const f16* __restrict__ cwt, const f16* __restrict__ kwt, const f16* __restrict__ fwh,
    const float* __restrict__ cg, const float* __restrict__ cb,
    const float* __restrict__ cm, const float* __restrict__ cv,
    const float* __restrict__ wg, const float* __restrict__ wb,
    const float* __restrict__ wm, const float* __restrict__ wvv,
    const float* __restrict__ fcb, const float* __restrict__ lng, const float* __restrict__ lnb,
    float* __restrict__ roi)
{
  __shared__ __align__(16) char smem[122368];
  f16*   Xt  = (f16*)smem;                 // stage-1 input (aliased by Yh later)
  f16*   Yh  = (f16*)smem;                 // [4][4608] catconv output
  f16*   cst = (f16*)(smem + 47872);       // concat of level-conv outputs
  float* scr = (float*)(smem + 118272);
  float* hs  = (float*)(smem + 120320);

  const int tid  = threadIdx.x, lane = tid & 63, w = tid >> 6;
  const int r16  = lane & 15, g4 = lane >> 4;
  const int nbase = blockIdx.x * G_;

  // ---- zero the pad rows (0-3, 40-43) of Xt and cst once ----
  for (int i = tid; i < G_*8*CPX; i += 512) {
    int rr = i / CPX, col = i - rr*CPX;
    int g = rr >> 3, r8 = rr & 7;
    int row = (r8 < 4) ? r8 : (36 + r8);
    Xt[(g*XROWS + row)*CPX + col] = (f16)0.f;
  }
  for (int i = tid; i < G_*8*CPC; i += 512) {
    int rr = i / CPC, col = i - rr*CPC;
    int g = rr >> 3, r8 = rr & 7;
    int row = (r8 < 4) ? r8 : (36 + r8);
    cst[(g*XROWS + row)*CPC + col] = (f16)0.f;
  }

  const int mh = w & 1, nq = w >> 1;
  const int nNT = (nq == 0) ? 3 : 2;
  int xoff[3], coffR[3], coffW[3], gq[3], sq[3];
  #pragma unroll
  for (int nl = 0; nl < 3; nl++) {
    int nt = nq + 4*nl; if (nt > 8) nt = 8;
    int q = nt*16 + r16;
    int g = q / 36, s = q - 36*g;
    gq[nl] = g; sq[nl] = s;
    xoff[nl]  = (g*XROWS + s)*CPX + g4*8;
    coffR[nl] = (g*XROWS + s)*CPC + g4*8;
    coffW[nl] = (g*XROWS + 4 + s)*CPC;
  }

  // ================= stage 1: per-level conv9 + BN + ReLU -> cst =================
  for (int lev = 0; lev < 3; lev++) {
    { // 4x4-block transpose loader: coalesced float4 reads, f16x4 LDS writes
      const float* rfl = (lev == 0 ? rf0 : (lev == 1 ? rf1 : rf2));
      #pragma unroll
      for (int it = 0; it < 3; it++) {
        int item = tid + 512*it;              // 4g x 32cb x 9sb = 1152 items
        if (item < 1152) {
          int g  = item / 288, rem = item - 288*g;
          int cb = rem / 9,  sb = rem - 9*cb;
          const float* src = rfl + (size_t)(nbase + g)*(C_*NS_) + (4*cb)*NS_ + 4*sb;
          float4 v0 = *(const float4*)(src + 0*NS_);
          float4 v1 = *(const float4*)(src + 1*NS_);
          float4 v2 = *(const float4*)(src + 2*NS_);
          float4 v3 = *(const float4*)(src + 3*NS_);
          f16* db = Xt + (g*XROWS + 4 + 4*sb)*CPX + 4*cb;
          f16x4 o;
          o[0]=(f16)v0.x; o[1]=(f16)v1.x; o[2]=(f16)v2.x; o[3]=(f16)v3.x; *(f16x4*)(db + 0*CPX) = o;
          o[0]=(f16)v0.y; o[1]=(f16)v1.y; o[2]=(f16)v2.y; o[3]=(f16)v3.y; *(f16x4*)(db + 1*CPX) = o;
          o[0]=(f16)v0.z; o[1]=(f16)v1.z; o[2]=(f16)v2.z; o[3]=(f16)v3.z; *(f16x4*)(db + 2*CPX) = o;
          o[0]=(f16)v0.w; o[1]=(f16)v1.w; o[2]=(f16)v2.w; o[3]=(f16)v3.w; *(f16x4*)(db + 3*CPX) = o;
        }
      }
    }
    __syncthreads();

    f32x4 acc[2][3];
    #pragma unroll
    for (int ml = 0; ml < 2; ml++)
      #pragma unroll
      for (int nl = 0; nl < 3; nl++) { f32x4 z = {0.f,0.f,0.f,0.f}; acc[ml][nl] = z; }

    const f16* wl = cwt + (size_t)lev*9*64*128;
    if (nNT == 3) s1_loop<3>(wl, Xt, xoff[0], xoff[1], xoff[2], mh, r16, g4, acc);
    else          s1_loop<2>(wl, Xt, xoff[0], xoff[1], xoff[2], mh, r16, g4, acc);

    #pragma unroll
    for (int ml = 0; ml < 2; ml++) {
      int mt  = 2*mh + ml;
      int ocl = mt*16 + g4*4;
      int ocg = lev*64 + ocl;
      float sc[4], sh[4];
      #pragma unroll
      for (int r = 0; r < 4; r++) {
        float s0 = cg[ocg+r] * rsqrtf(cv[ocg+r] + EPS_);
        sc[r] = s0; sh[r] = cb[ocg+r] - cm[ocg+r]*s0;
      }
      #pragma unroll
      for (int nl = 0; nl < 3; nl++) if (nl < nNT) {
        f16x4 o;
        #pragma unroll
        for (int r = 0; r < 4; r++)
          o[r] = (f16)fmaxf(fmaf(sc[r], acc[ml][nl][r], sh[r]), 0.f);
        *(f16x4*)(cst + coffW[nl] + lev*64 + ocl) = o;
      }
    }
    __syncthreads();
  }

  // ================= stage 2: catconv9 + BN + ReLU -> Yh (f16) =================
  {
    f32x4 acc[4][3];
    #pragma unroll
    for (int ml = 0; ml < 4; ml++)
      #pragma unroll
      for (int nl = 0; nl < 3; nl++) { f32x4 z = {0.f,0.f,0.f,0.f}; acc[ml][nl] = z; }

    if (nNT == 3) s2_loop<3>(kwt, cst, coffR[0], coffR[1], coffR[2], mh, r16, g4, acc);
    else          s2_loop<2>(kwt, cst, coffR[0], coffR[1], coffR[2], mh, r16, g4, acc);

    #pragma unroll
    for (int ml = 0; ml < 4; ml++) {
      int oc0 = (4*mh + ml)*16 + g4*4;
      float sc[4], sh[4];
      #pragma unroll
      for (int r = 0; r < 4; r++) {
        float s0 = wg[oc0+r] * rsqrtf(wvv[oc0+r] + EPS_);
        sc[r] = s0; sh[r] = wb[oc0+r] - wm[oc0+r]*s0;
      }
      #pragma unroll
      for (int nl = 0; nl < 3; nl++) if (nl < nNT) {
        int yb = gq[nl]*4608 + oc0*36 + sq[nl];
        #pragma unroll
        for (int r = 0; r < 4; r++)
          Yh[yb + r*36] = (f16)fmaxf(fmaf(sc[r], acc[ml][nl][r], sh[r]), 0.f);
      }
    }
  }
  __syncthreads();

  // ================= stage 3: fc via MFMA (N=4 of 16 used) + LN + ReLU =========
  {
    const int mtp = w & 3, kh = w >> 2;
    const int gcol = r16 & 3;
    f32x4 fa0 = {0.f,0.f,0.f,0.f}, fa1 = fa0;
    const f16* bb0 = Yh + gcol*4608 + kh*2304 + g4*8;
    const f16* aw0 = fwh + (size_t)((2*mtp+0)*16 + r16)*4608 + kh*2304 + g4*8;
    const f16* aw1 = fwh + (size_t)((2*mtp+1)*16 + r16)*4608 + kh*2304 + g4*8;
    #pragma unroll
    for (int ks = 0; ks < 72; ks++) {
      int k0 = ks*32;
      f16x8 bb = *(const f16x8*)(bb0 + k0);
      f16x8 a0 = *(const f16x8*)(aw0 + k0);
      f16x8 a1 = *(const f16x8*)(aw1 + k0);
      fa0 = MFMA16(a0, bb, fa0);
      fa1 = MFMA16(a1, bb, fa1);
    }
    if (kh == 1 && r16 < 4) {
      #pragma unroll
      for (int r = 0; r < 4; r++) {
        scr[((2*mtp+0)*16 + g4*4 + r)*4 + r16] = fa0[r];
        scr[((2*mtp+1)*16 + g4*4 + r)*4 + r16] = fa1[r];
      }
    }
    __syncthreads();
    if (kh == 0 && r16 < 4) {
      #pragma unroll
      for (int r = 0; r < 4; r++) {
        int f0 = (2*mtp+0)*16 + g4*4 + r;
        int f1 = (2*mtp+1)*16 + g4*4 + r;
        hs[r16*128 + f0] = fa0[r] + scr[f0*4 + r16] + fcb[f0];
        hs[r16*128 + f1] = fa1[r] + scr[f1*4 + r16] + fcb[f1];
      }
    }
  }
  __syncthreads();

  { // LayerNorm + ReLU
    int g = w >> 1, f = (w & 1)*64 + lane;
    float h = hs[g*128 + f];
    float s1 = h, s2 = h*h;
    #pragma unroll
    for (int off = 32; off; off >>= 1) {
      s1 += __shfl_xor(s1, off, 64);
      s2 += __shfl_xor(s2, off, 64);
    }
    if (lane == 0) { scr[w*2] = s1; scr[w*2+1] = s2; }
    __syncthreads();
    float S1 = scr[(2*g)*2]   + scr[(2*g+1)*2];
    float S2 = scr[(2*g)*2+1] + scr[(2*g+1)*2+1];
    float mu  = S1 * (1.f/128.f);
    float var = S2 * (1.f/128.f) - mu*mu;
    float rr  = rsqrtf(var + EPS_);
    roi[(size_t)(nbase + g)*FCH_ + f] = fmaxf((h - mu)*rr*lng[f] + lnb[f], 0.f);
  }
}

// ---------------------------------------------------------------------------
// K2: key/val projections at 250 sample points -> f16 transposed layouts for
// the MFMA attention: kT[b][l][c] (l padded to 256 w/ zeros), vT[b][c][l].
// grid (256, B), block 128.
// ---------------------------------------------------------------------------
__global__ __launch_bounds__(128) void k_kv(
    const float* __restrict__ fmap,
    const float* __restrict__ kw, const float* __restrict__ kg, const float* __restrict__ kbeta,
    const float* __restrict__ km, const float* __restrict__ kvv,
    const float* __restrict__ vw, const float* __restrict__ vb,
    f16* __restrict__ kT, f16* __restrict__ vT)
{
  int l = blockIdx.x, b = blockIdx.y, tid = threadIdx.x;
  if (l >= L_) {   // zero pads so MFMA N-padding is exact
    kT[((size_t)b*256 + l)*C_ + tid] = (f16)0.f;
    vT[((size_t)b*C_ + tid)*256 + l] = (f16)0.f;
    return;
  }
  int r = l / RW_, s = l % RW_;
  int pix = (r * FH_ / RH_) * FW_ + (s * FW_ / RW_);
  __shared__ float fs[C_];
  fs[tid] = fmap[((size_t)b * C_ + tid) * (FH_ * FW_) + pix];
  __syncthreads();

  int c = tid;
  const float4* kwp = reinterpret_cast<const float4*>(kw + (size_t)c * C_);
  const float4* vwp = reinterpret_cast<const float4*>(vw + (size_t)c * C_);
  float kk = 0.f, vv = 0.f;
  for (int i = 0; i < 32; i++) {
    float4 ku = kwp[i]; float4 vu = vwp[i];
    const float* fb = fs + i * 4;
    kk = fmaf(ku.x, fb[0], kk);  vv = fmaf(vu.x, fb[0], vv);
    kk = fmaf(ku.y, fb[1], kk);  vv = fmaf(vu.y, fb[1], vv);
    kk = fmaf(ku.z, fb[2], kk);  vv = fmaf(vu.z, fb[2], vv);
    kk = fmaf(ku.w, fb[3], kk);  vv = fmaf(vu.w, fb[3], vv);
  }
  float scale = kg[c] * rsqrtf(kvv[c] + EPS_);
  float shift = kbeta[c] - km[c] * scale;
  kT[((size_t)b*256 + l)*C_ + c] = (f16)fmaxf(fmaf(scale, kk, shift), 0.f);
  vT[((size_t)b*C_ + c)*256 + l] = (f16)(vv + vb[c]);
}

// ---------------------------------------------------------------------------
// K3 (MFMA): attention. grid (6, B), block 256 (4 waves); 32 q-rows per block.
// S = Q.K^T (M=32,N=256(250),K=128); softmax; ctx = P.V (M=32,N=128,K=256).
// In-place residual update on roi.
// ---------------------------------------------------------------------------
__global__ __launch_bounds__(256) void k_attn(
    const f16* __restrict__ kT, const f16* __restrict__ vT,
    const float* __restrict__ qw, const float* __restrict__ qb,
    const float* __restrict__ gw, const float* __restrict__ gb,
    float* __restrict__ out)
{
  int qt = blockIdx.x, b = blockIdx.y;
  int np0 = qt * 32;
  int tid = threadIdx.x, lane = tid & 63, w = tid >> 6;
  int r16 = lane & 15, g4 = lane >> 4;

  __shared__ __align__(16) f16   qA[32*136];   // Q f16, padded stride
  __shared__ __align__(16) float S[32*264];    // scores f32
  __shared__ __align__(16) f16   P[32*264];    // softmax probs f16
  __shared__ float sinv[32];

  { // q = relu(roi*qw+qb) -> qA ; thread: m = tid>>3, 16 channels
    int m = tid >> 3, c0 = (tid & 7) * 16;
    int np = np0 + m;
    const float* rp = out + ((size_t)b*NP_ + np)*C_ + c0;
    float aa = qw[np], bb = qb[np];
    f16* dst = qA + m*136 + c0;
    #pragma unroll
    for (int j = 0; j < 16; j++) dst[j] = (f16)fmaxf(fmaf(rp[j], aa, bb), 0.f);
  }
  __syncthreads();

  const f16* kTb = kT + (size_t)b*256*C_;
  const f16* vTb = vT + (size_t)b*C_*256;

  { // S = Q.K^T : wave w -> mt = w&1, nt = (w>>1)*8 + j
    int mt = w & 1, ntg = w >> 1;
    f32x4 acc[8];
    #pragma unroll
    for (int j = 0; j < 8; j++) { f32x4 z = {0.f,0.f,0.f,0.f}; acc[j] = z; }
    #pragma unroll
    for (int ks = 0; ks < 4; ks++) {
      f16x8 a = *(const f16x8*)(qA + (mt*16 + r16)*136 + ks*32 + g4*8);
      #pragma unroll
      for (int j = 0; j < 8; j++) {
        int nt = ntg*8 + j;
        f16x8 bf = *(const f16x8*)(kTb + (size_t)(nt*16 + r16)*C_ + ks*32 + g4*8);
        acc[j] = MFMA16(a, bf, acc[j]);
      }
    }
    #pragma unroll
    for (int j = 0; j < 8; j++) {
      int nt = ntg*8 + j;
      #pragma unroll
      for (int r = 0; r < 4; r++)
        S[(mt*16 + g4*4 + r)*264 + nt*16 + r16] = acc[j][r];
    }
  }
  __syncthreads();

  { // softmax: 8 lanes per row; n = sub + 8k keeps banks spread
    int row = tid >> 3, sub = tid & 7;
    const float sc = 0.088388347648318447f;   // 1/sqrt(128)
    float v[32];
    float mx = -1e30f;
    #pragma unroll
    for (int k = 0; k < 32; k++) {
      int n = sub + 8*k;
      float x = (n < L_) ? S[row*264 + n]*sc : -1e30f;
      v[k] = x;
      mx = fmaxf(mx, x);
    }
    #pragma unroll
    for (int off = 1; off < 8; off <<= 1) mx = fmaxf(mx, __shfl_xor(mx, off, 64));
    float s = 0.f;
    #pragma unroll
    for (int k = 0; k < 32; k++) {
      int n = sub + 8*k;
      float e = (n < L_) ? __expf(v[k] - mx) : 0.f;
      P[row*264 + n] = (f16)e;
      s += e;
    }
    #pragma unroll
    for (int off = 1; off < 8; off <<= 1) s += __shfl_xor(s, off, 64);
    if (sub == 0) sinv[row] = 1.f / s;
  }
  __syncthreads();

  { // ctx = P.V : wave w -> mt = w&1, nt = (w>>1)*4 + j ; epilogue in-place
    int mt = w & 1, ntg = w >> 1;
    f32x4 acc[4];
    #pragma unroll
    for (int j = 0; j < 4; j++) { f32x4 z = {0.f,0.f,0.f,0.f}; acc[j] = z; }
    #pragma unroll
    for (int ks = 0; ks < 8; ks++) {
      f16x8 a = *(const f16x8*)(P + (mt*16 + r16)*264 + ks*32 + g4*8);
      #pragma unroll
      for (int j = 0; j < 4; j++) {
        int nt = ntg*4 + j;
        f16x8 bf = *(const f16x8*)(vTb + (size_t)(nt*16 + r16)*256 + ks*32 + g4*8);
        acc[j] = MFMA16(a, bf, acc[j]);
      }
    }
    #pragma unroll
    for (int r = 0; r < 4; r++) {
      int m = mt*16 + g4*4 + r;
      int np = np0 + m;
      float gwv = gw[np], gbv = gb[np], si = sinv[m];
      float* rp = out + ((size_t)b*NP_ + np)*C_;
      #pragma unroll
      for (int j = 0; j < 4; j++) {
        int c = (ntg*4 + j)*16 + r16;
        rp[c] = rp[c] + acc[j][r]*si*gwv + gbv;
      }
    }
  }
}

// ---------------------------------------------------------------------------
extern "C" void kernel_launch(void* const* d_in, const int* in_sizes, int n_in,
                              void* d_out, int out_size, void* d_ws, size_t ws_size,
                              hipStream_t stream)
{
  const float* rf0    = (const float*)d_in[0];
  const float* rf1    = (const float*)d_in[1];
  const float* rf2    = (const float*)d_in[2];
  const float* fmap   = (const float*)d_in[3];
  const float* conv_w = (const float*)d_in[4];
  const float* conv_g = (const float*)d_in[5];
  const float* conv_b = (const float*)d_in[6];
  const float* conv_m = (const float*)d_in[7];
  const float* conv_v = (const float*)d_in[8];
  const float* cat_w  = (const float*)d_in[9];
  const float* cat_g  = (const float*)d_in[10];
  const float* cat_b  = (const float*)d_in[11];
  const float* cat_m  = (const float*)d_in[12];
  const float* cat_v  = (const float*)d_in[13];
  const float* fc_w   = (const float*)d_in[14];
  const float* fc_b   = (const float*)d_in[15];
  const float* ln_g   = (const float*)d_in[16];
  const float* ln_b   = (const float*)d_in[17];
  const float* key_w  = (const float*)d_in[18];
  const float* key_g  = (const float*)d_in[19];
  const float* key_be = (const float*)d_in[20];
  const float* key_m  = (const float*)d_in[21];
  const float* key_v  = (const float*)d_in[22];
  const float* q_w    = (const float*)d_in[23];
  const float* q_b    = (const float*)d_in[24];
  const float* val_w  = (const float*)d_in[25];
  const float* val_b  = (const float*)d_in[26];
  const float* gate_w = (const float*)d_in[27];
  const float* gate_b = (const float*)d_in[28];
  // d_in[29] = layer_index (==2): reference applies cat_w after concat. Unused.

  float* roi  = (float*)d_out;
  char*  ws   = (char*)d_ws;
  f16*   kT   = (f16*)(ws + WS_KT);
  f16*   vT   = (f16*)(ws + WS_VT);
  f16*   cwt  = (f16*)(ws + WS_CONVWT);
  f16*   kwt  = (f16*)(ws + WS_CATWT);
  f16*   fwh  = (f16*)(ws + WS_FCWH);

  k_prep<<<dim3(4032), 256, 0, stream>>>(conv_w, cat_w, fc_w, cwt, kwt, fwh);
  k_kv<<<dim3(256, B_), 128, 0, stream>>>(fmap, key_w, key_g, key_be, key_m, key_v,
                                          val_w, val_b, kT, vT);
  k_roi<<<dim3(NR_/G_), 512, 0, stream>>>(rf0, rf1, rf2, cwt, kwt, fwh,
                                          conv_g, conv_b, conv_m, conv_v,
                                          cat_g, cat_b, cat_m, cat_v,
                                          fc_b, ln_g, ln_b, roi);
  k_attn<<<dim3(6, B_), 256, 0, stream>>>(kT, vT, q_w, q_b, gate_w, gate_b, roi);
}